// Round 4
// baseline (759.975 us; speedup 1.0000x reference)
//
#include <hip/hip_runtime.h>
#include <math.h>

#define NSPEC 8192
#define NRXN  16384
#define NBAL  7680
#define NUNBAL 512

#define NBLOCK  2048
#define NTHREAD 256
#define NTHREADS_TOTAL (NBLOCK * NTHREAD)        // 524288
#define NWAVES_TOTAL   (NTHREADS_TOTAL / 64)     // 8192
#define TSLOTS 8                                 // per-thread COO slots (mean 0.41)

#define NVEC4  ((long long)NSPEC * NRXN / 4)     // 33,554,432 vec4s
#define CHUNK  256                               // vec4s per wave-chunk (4 KB)
#define NCHUNK (NVEC4 / CHUNK)                   // 131072

// workspace byte offsets
#define OFF_LOGC  0u                             // float[8192]
#define OFF_LOGV  32768u                         // float[16384] (log domain)
#define OFF_ACC   98304u                         // float[8192]
#define OFF_CNT   131072u                        // unsigned[1] spill counter
#define OFF_TCNT  131088u                        // unsigned[524288] per-thread counts
#define OFF_SLICE (OFF_TCNT + NTHREADS_TOTAL * 4u)            // 2228240
#define OFF_SPILL (OFF_SLICE + NTHREADS_TOTAL * TSLOTS * 4u)  // 19005456

// pack: s(13b) << 17 | r(14b) << 3 | (val+2)(3b)

__global__ void k_init(const float* __restrict__ cb, const int* __restrict__ bidx,
                       const int* __restrict__ uidx, const float* __restrict__ lcu,
                       const float* __restrict__ lkcat,
                       float* __restrict__ logc, float* __restrict__ logv,
                       float* __restrict__ acc, unsigned* __restrict__ cnt) {
    int i = blockIdx.x * blockDim.x + threadIdx.x;
    if (i == 0) *cnt = 0u;
    if (i < NRXN)  logv[i] = lkcat[i];
    if (i < NSPEC) acc[i] = 0.0f;
    if (i < NBAL)  logc[bidx[i]] = logf(cb[i]);
    if (i < NUNBAL) logc[uidx[i]] = lcu[i];   // log(exp(x)) == x
}

__device__ __forceinline__ void proc_group(int4 g, long long idx,
                                           const float* __restrict__ logc,
                                           float* __restrict__ logv,
                                           unsigned* __restrict__ slice,
                                           unsigned& lc,
                                           unsigned* __restrict__ spillcnt,
                                           unsigned* __restrict__ spill,
                                           unsigned spillcap) {
    if ((g.x | g.y | g.z | g.w) == 0) return;      // 97.5% skip (+0.0 only zero)
    const int s = (int)(idx >> 12);                // 4096 vec4s per species row
    const int rbase = ((int)idx & 4095) << 2;
    const float lcs = logc[s];
    const int vb[4] = {g.x, g.y, g.z, g.w};
    #pragma unroll
    for (int j = 0; j < 4; ++j) {
        if (vb[j] != 0) {
            float val = __int_as_float(vb[j]);
            int iv = (int)val;                     // exact: S is integer-valued
            if (val < 0.0f)
                atomicAdd(&logv[rbase + j], -val * lcs);
            unsigned e = ((unsigned)s << 17) | ((unsigned)(rbase + j) << 3) |
                         (unsigned)(iv + 2);
            if (lc < TSLOTS) {
                slice[lc] = e;
            } else {                               // ~1e-9 probability path
                unsigned sp = atomicAdd(spillcnt, 1u);
                if (sp < spillcap) spill[sp] = e;
            }
            lc++;
        }
    }
}

// single pass over S: 4 independent 1KB wave-loads per iteration, no cross-lane
// ops, per-thread private COO slices (no shared counters in the hot path)
__global__ __launch_bounds__(256) void k_scan(const float* __restrict__ S,
                                              const float* __restrict__ logc,
                                              float* __restrict__ logv,
                                              unsigned* __restrict__ tcnt,
                                              unsigned* __restrict__ slices,
                                              unsigned* __restrict__ spillcnt,
                                              unsigned* __restrict__ spill,
                                              unsigned spillcap) {
    const unsigned tid = blockIdx.x * blockDim.x + threadIdx.x;
    const unsigned wid = tid >> 6;
    const int lane = threadIdx.x & 63;
    const int4* S4 = (const int4*)S;
    unsigned* const slice = slices + (size_t)tid * TSLOTS;
    unsigned lc = 0;
    for (long long c = wid; c < NCHUNK; c += NWAVES_TOTAL) {
        const long long b = c * CHUNK + lane;
        int4 g0 = S4[b];
        int4 g1 = S4[b + 64];
        int4 g2 = S4[b + 128];
        int4 g3 = S4[b + 192];
        proc_group(g0, b,       logc, logv, slice, lc, spillcnt, spill, spillcap);
        proc_group(g1, b + 64,  logc, logv, slice, lc, spillcnt, spill, spillcap);
        proc_group(g2, b + 128, logc, logv, slice, lc, spillcnt, spill, spillcap);
        proc_group(g3, b + 192, logc, logv, slice, lc, spillcnt, spill, spillcap);
    }
    tcnt[tid] = (lc < TSLOTS) ? lc : TSLOTS;
}

// replay COO slices; v = expf(logv) computed inline (saves a dispatch)
__global__ __launch_bounds__(256) void k_scatter(const unsigned* __restrict__ slices,
                                                 const unsigned* __restrict__ tcnt,
                                                 const unsigned* __restrict__ spill,
                                                 const unsigned* __restrict__ spillcnt,
                                                 unsigned spillcap,
                                                 const float* __restrict__ logv,
                                                 float* __restrict__ acc) {
    unsigned idx = blockIdx.x * blockDim.x + threadIdx.x;
    if (idx < (unsigned)NTHREADS_TOTAL * TSLOTS) {
        unsigned t = idx >> 3, slot = idx & 7u;    // TSLOTS == 8
        if (slot < tcnt[t]) {
            unsigned e = slices[idx];
            int s = (int)(e >> 17);
            int r = (int)((e >> 3) & 0x3FFFu);
            float iv = (float)((int)(e & 7u) - 2);
            atomicAdd(&acc[s], iv * expf(logv[r]));
        }
    }
    unsigned n = *spillcnt;
    if (n > spillcap) n = spillcap;
    unsigned stride = gridDim.x * blockDim.x;
    for (unsigned i = idx; i < n; i += stride) {
        unsigned e = spill[i];
        int s = (int)(e >> 17);
        int r = (int)((e >> 3) & 0x3FFFu);
        float iv = (float)((int)(e & 7u) - 2);
        atomicAdd(&acc[s], iv * expf(logv[r]));
    }
}

// ---- fallback (tiny ws): no COO, two full passes over S ----
__global__ __launch_bounds__(256) void k_scan_noent(const float* __restrict__ S,
                                                    const float* __restrict__ logc,
                                                    float* __restrict__ logv) {
    const long long stride = (long long)gridDim.x * blockDim.x;
    for (long long i = (long long)blockIdx.x * blockDim.x + threadIdx.x;
         i < NVEC4; i += stride) {
        const float4 f = ((const float4*)S)[i];
        const float vals[4] = {f.x, f.y, f.z, f.w};
        if (f.x < 0.0f || f.y < 0.0f || f.z < 0.0f || f.w < 0.0f) {
            int s = (int)(i >> 12);
            int rbase = ((int)i & 4095) << 2;
            #pragma unroll
            for (int j = 0; j < 4; ++j)
                if (vals[j] < 0.0f)
                    atomicAdd(&logv[rbase + j], -vals[j] * logc[s]);
        }
    }
}

__global__ __launch_bounds__(256) void k_pass2(const float* __restrict__ S,
                                               const float* __restrict__ logv,
                                               float* __restrict__ acc) {
    const long long stride = (long long)gridDim.x * blockDim.x;
    for (long long i = (long long)blockIdx.x * blockDim.x + threadIdx.x;
         i < NVEC4; i += stride) {
        const float4 f = ((const float4*)S)[i];
        const float vals[4] = {f.x, f.y, f.z, f.w};
        if (f.x != 0.0f || f.y != 0.0f || f.z != 0.0f || f.w != 0.0f) {
            int s = (int)(i >> 12);
            int rbase = ((int)i & 4095) << 2;
            #pragma unroll
            for (int j = 0; j < 4; ++j)
                if (vals[j] != 0.0f)
                    atomicAdd(&acc[s], vals[j] * expf(logv[rbase + j]));
        }
    }
}

__global__ void k_gather(const float* __restrict__ acc,
                         const int* __restrict__ bidx,
                         float* __restrict__ out) {
    int i = blockIdx.x * blockDim.x + threadIdx.x;
    if (i < NBAL) out[i] = acc[bidx[i]];
}

extern "C" void kernel_launch(void* const* d_in, const int* in_sizes, int n_in,
                              void* d_out, int out_size, void* d_ws, size_t ws_size,
                              hipStream_t stream) {
    const float* cb    = (const float*)d_in[0];
    const float* S     = (const float*)d_in[1];
    const int*   bidx  = (const int*)d_in[2];
    const int*   uidx  = (const int*)d_in[3];
    const float* lcu   = (const float*)d_in[4];
    const float* lkcat = (const float*)d_in[5];
    float* out = (float*)d_out;

    char* ws = (char*)d_ws;
    float*    logc   = (float*)(ws + OFF_LOGC);
    float*    logv   = (float*)(ws + OFF_LOGV);
    float*    acc    = (float*)(ws + OFF_ACC);
    unsigned* cnt    = (unsigned*)(ws + OFF_CNT);
    unsigned* tcnt   = (unsigned*)(ws + OFF_TCNT);
    unsigned* slices = (unsigned*)(ws + OFF_SLICE);
    unsigned* spill  = (unsigned*)(ws + OFF_SPILL);

    k_init<<<(NRXN + 255) / 256, 256, 0, stream>>>(cb, bidx, uidx, lcu, lkcat,
                                                   logc, logv, acc, cnt);
    if (ws_size >= OFF_SPILL + 65536u) {
        unsigned spillcap = (unsigned)((ws_size - OFF_SPILL) / 4);
        k_scan<<<NBLOCK, NTHREAD, 0, stream>>>(S, logc, logv, tcnt, slices,
                                               cnt, spill, spillcap);
        k_scatter<<<(NTHREADS_TOTAL * TSLOTS) / 256, 256, 0, stream>>>(
            slices, tcnt, spill, cnt, spillcap, logv, acc);
    } else {
        k_scan_noent<<<NBLOCK, NTHREAD, 0, stream>>>(S, logc, logv);
        k_pass2<<<NBLOCK, NTHREAD, 0, stream>>>(S, logv, acc);
    }
    k_gather<<<(NBAL + 255) / 256, 256, 0, stream>>>(acc, bidx, out);
}

// Round 5
// 729.885 us; speedup vs baseline: 1.0412x; 1.0412x over previous
//
#include <hip/hip_runtime.h>
#include <math.h>

#define NSPEC 8192
#define NRXN  16384
#define NBAL  7680
#define NUNBAL 512

#define NBLOCK  2048
#define NTHREAD 256
#define NTHREADS_TOTAL (NBLOCK * NTHREAD)        // 524288
#define NWAVES_TOTAL   (NTHREADS_TOTAL / 64)     // 8192
#define TSLOTS 8                                 // per-thread COO slots (mean 0.41)

#define NVEC4  (NSPEC * NRXN / 4)                // 33,554,432 — fits in int
#define CHUNK  256                               // vec4s per wave-chunk (4 KB); divides 4096 -> chunk-uniform row
#define NCHUNK (NVEC4 / CHUNK)                   // 131072

// workspace byte offsets
#define OFF_LOGC  0u                             // float[8192]
#define OFF_LOGV  32768u                         // float[16384] (log domain)
#define OFF_ACC   98304u                         // float[8192]
#define OFF_CNT   131072u                        // unsigned[1] spill counter
#define OFF_TCNT  131088u                        // unsigned[524288]
#define OFF_SLICE (OFF_TCNT + NTHREADS_TOTAL * 4u)            // 2228240
#define OFF_SPILL (OFF_SLICE + NTHREADS_TOTAL * TSLOTS * 4u)  // 19005456

// pack: s(13b) << 17 | r(14b) << 3 | (val+2)(3b)

__global__ void k_init(const float* __restrict__ cb, const int* __restrict__ bidx,
                       const int* __restrict__ uidx, const float* __restrict__ lcu,
                       const float* __restrict__ lkcat,
                       float* __restrict__ logc, float* __restrict__ logv,
                       float* __restrict__ acc, unsigned* __restrict__ cnt) {
    int i = blockIdx.x * blockDim.x + threadIdx.x;
    if (i == 0) *cnt = 0u;
    if (i < NRXN)  logv[i] = lkcat[i];
    if (i < NSPEC) acc[i] = 0.0f;
    if (i < NBAL)  logc[bidx[i]] = logf(cb[i]);
    if (i < NUNBAL) logc[uidx[i]] = lcu[i];   // log(exp(x)) == x
}

__device__ __forceinline__ void proc_group(int4 g, int idx, int s, float lcs,
                                           float* __restrict__ logv,
                                           unsigned* __restrict__ slice,
                                           unsigned& lc,
                                           unsigned* __restrict__ spillcnt,
                                           unsigned* __restrict__ spill,
                                           unsigned spillcap) {
    if ((g.x | g.y | g.z | g.w) == 0) return;      // ~97.5% of vec4s skip
    const int rbase = (idx & 4095) << 2;
    const int vb[4] = {g.x, g.y, g.z, g.w};
    #pragma unroll
    for (int j = 0; j < 4; ++j) {
        if (vb[j] != 0) {
            float val = __int_as_float(vb[j]);
            int iv = (int)val;                     // exact: S is integer-valued
            if (val < 0.0f)
                atomicAdd(&logv[rbase + j], -val * lcs);
            unsigned e = ((unsigned)s << 17) | ((unsigned)(rbase + j) << 3) |
                         (unsigned)(iv + 2);
            if (lc < TSLOTS) {
                slice[lc] = e;
            } else {                               // ~1e-10/thread path
                unsigned sp = atomicAdd(spillcnt, 1u);
                if (sp < spillcap) spill[sp] = e;
            }
            lc++;
        }
    }
}

// one streaming pass over S: 4 outstanding 1KB wave-loads, 32-bit indexing,
// chunk-uniform species row (s, logc[s] hoisted), per-thread private COO
__global__ __launch_bounds__(256) void k_scan(const float* __restrict__ S,
                                              const float* __restrict__ logc,
                                              float* __restrict__ logv,
                                              unsigned* __restrict__ tcnt,
                                              unsigned* __restrict__ slices,
                                              unsigned* __restrict__ spillcnt,
                                              unsigned* __restrict__ spill,
                                              unsigned spillcap) {
    const int tid = blockIdx.x * blockDim.x + threadIdx.x;
    const int wid = tid >> 6;
    const int lane = threadIdx.x & 63;
    const int4* S4 = (const int4*)S;
    unsigned* const slice = slices + (size_t)tid * TSLOTS;
    unsigned lc = 0;
    for (int c = wid; c < NCHUNK; c += NWAVES_TOTAL) {
        const int b = c * CHUNK + lane;            // vec4 index, 32-bit
        int4 g0 = S4[b];
        int4 g1 = S4[b + 64];
        int4 g2 = S4[b + 128];
        int4 g3 = S4[b + 192];
        const int s = b >> 12;                     // chunk never crosses a row
        const float lcs = logc[s];                 // wave-broadcast load
        proc_group(g0, b,       s, lcs, logv, slice, lc, spillcnt, spill, spillcap);
        proc_group(g1, b + 64,  s, lcs, logv, slice, lc, spillcnt, spill, spillcap);
        proc_group(g2, b + 128, s, lcs, logv, slice, lc, spillcnt, spill, spillcap);
        proc_group(g3, b + 192, s, lcs, logv, slice, lc, spillcnt, spill, spillcap);
    }
    tcnt[tid] = (lc < TSLOTS) ? lc : TSLOTS;
}

// replay COO: one thread per source-thread slice; v = expf(logv) inline
__global__ __launch_bounds__(256) void k_scatter(const unsigned* __restrict__ slices,
                                                 const unsigned* __restrict__ tcnt,
                                                 const unsigned* __restrict__ spill,
                                                 const unsigned* __restrict__ spillcnt,
                                                 unsigned spillcap,
                                                 const float* __restrict__ logv,
                                                 float* __restrict__ acc) {
    const unsigned t = blockIdx.x * blockDim.x + threadIdx.x;
    if (t < (unsigned)NTHREADS_TOTAL) {
        unsigned cnt = tcnt[t];                    // <= TSLOTS by construction
        const unsigned* sl = slices + (size_t)t * TSLOTS;
        for (unsigned k = 0; k < cnt; ++k) {
            unsigned e = sl[k];
            int s = (int)(e >> 17);
            int r = (int)((e >> 3) & 0x3FFFu);
            float iv = (float)((int)(e & 7u) - 2);
            atomicAdd(&acc[s], iv * expf(logv[r]));
        }
    }
    unsigned n = *spillcnt;
    if (n > spillcap) n = spillcap;
    unsigned stride = gridDim.x * blockDim.x;
    for (unsigned i = t; i < n; i += stride) {
        unsigned e = spill[i];
        int s = (int)(e >> 17);
        int r = (int)((e >> 3) & 0x3FFFu);
        float iv = (float)((int)(e & 7u) - 2);
        atomicAdd(&acc[s], iv * expf(logv[r]));
    }
}

// ---- fallback (tiny ws): no COO, two full passes over S ----
__global__ __launch_bounds__(256) void k_scan_noent(const float* __restrict__ S,
                                                    const float* __restrict__ logc,
                                                    float* __restrict__ logv) {
    const long long stride = (long long)gridDim.x * blockDim.x;
    for (long long i = (long long)blockIdx.x * blockDim.x + threadIdx.x;
         i < NVEC4; i += stride) {
        const float4 f = ((const float4*)S)[i];
        const float vals[4] = {f.x, f.y, f.z, f.w};
        if (f.x < 0.0f || f.y < 0.0f || f.z < 0.0f || f.w < 0.0f) {
            int s = (int)(i >> 12);
            int rbase = ((int)i & 4095) << 2;
            #pragma unroll
            for (int j = 0; j < 4; ++j)
                if (vals[j] < 0.0f)
                    atomicAdd(&logv[rbase + j], -vals[j] * logc[s]);
        }
    }
}

__global__ __launch_bounds__(256) void k_pass2(const float* __restrict__ S,
                                               const float* __restrict__ logv,
                                               float* __restrict__ acc) {
    const long long stride = (long long)gridDim.x * blockDim.x;
    for (long long i = (long long)blockIdx.x * blockDim.x + threadIdx.x;
         i < NVEC4; i += stride) {
        const float4 f = ((const float4*)S)[i];
        const float vals[4] = {f.x, f.y, f.z, f.w};
        if (f.x != 0.0f || f.y != 0.0f || f.z != 0.0f || f.w != 0.0f) {
            int s = (int)(i >> 12);
            int rbase = ((int)i & 4095) << 2;
            #pragma unroll
            for (int j = 0; j < 4; ++j)
                if (vals[j] != 0.0f)
                    atomicAdd(&acc[s], vals[j] * expf(logv[rbase + j]));
        }
    }
}

__global__ void k_gather(const float* __restrict__ acc,
                         const int* __restrict__ bidx,
                         float* __restrict__ out) {
    int i = blockIdx.x * blockDim.x + threadIdx.x;
    if (i < NBAL) out[i] = acc[bidx[i]];
}

extern "C" void kernel_launch(void* const* d_in, const int* in_sizes, int n_in,
                              void* d_out, int out_size, void* d_ws, size_t ws_size,
                              hipStream_t stream) {
    const float* cb    = (const float*)d_in[0];
    const float* S     = (const float*)d_in[1];
    const int*   bidx  = (const int*)d_in[2];
    const int*   uidx  = (const int*)d_in[3];
    const float* lcu   = (const float*)d_in[4];
    const float* lkcat = (const float*)d_in[5];
    float* out = (float*)d_out;

    char* ws = (char*)d_ws;
    float*    logc   = (float*)(ws + OFF_LOGC);
    float*    logv   = (float*)(ws + OFF_LOGV);
    float*    acc    = (float*)(ws + OFF_ACC);
    unsigned* cnt    = (unsigned*)(ws + OFF_CNT);
    unsigned* tcnt   = (unsigned*)(ws + OFF_TCNT);
    unsigned* slices = (unsigned*)(ws + OFF_SLICE);
    unsigned* spill  = (unsigned*)(ws + OFF_SPILL);

    k_init<<<(NRXN + 255) / 256, 256, 0, stream>>>(cb, bidx, uidx, lcu, lkcat,
                                                   logc, logv, acc, cnt);
    if (ws_size >= OFF_SPILL + 65536u) {
        unsigned spillcap = (unsigned)((ws_size - OFF_SPILL) / 4);
        k_scan<<<NBLOCK, NTHREAD, 0, stream>>>(S, logc, logv, tcnt, slices,
                                               cnt, spill, spillcap);
        k_scatter<<<NBLOCK, NTHREAD, 0, stream>>>(slices, tcnt, spill, cnt,
                                                  spillcap, logv, acc);
    } else {
        k_scan_noent<<<NBLOCK, NTHREAD, 0, stream>>>(S, logc, logv);
        k_pass2<<<NBLOCK, NTHREAD, 0, stream>>>(S, logv, acc);
    }
    k_gather<<<(NBAL + 255) / 256, 256, 0, stream>>>(acc, bidx, out);
}